// Round 7
// baseline (2714.790 us; speedup 1.0000x reference)
//
#include <hip/hip_runtime.h>

#define BATCH 256
#define TT 512
#define CIN 512
#define UU 512
#define ZN 2048
#define BT (BATCH*TT)

typedef __attribute__((ext_vector_type(8))) short short8;
typedef __attribute__((ext_vector_type(4))) float f32x4;

__device__ __forceinline__ short f2bf(float f){
  unsigned u = __float_as_uint(f);
  u += 0x7fffu + ((u >> 16) & 1u);   // round-to-nearest-even
  return (short)(u >> 16);
}
__device__ __forceinline__ float bf2f(unsigned short s){
  unsigned u = ((unsigned)s) << 16;
  return __uint_as_float(u);
}

#define GLD16(g, l) __builtin_amdgcn_global_load_lds( \
    (const __attribute__((address_space(1))) void*)(g), \
    (__attribute__((address_space(3))) void*)(l), 16, 0, 0)

// coherent (device-scope, MALL) 16B load with immediate offset
#define CLOAD(dst, p, OFFSTR) asm volatile( \
    "global_load_dwordx4 %0, %1, off offset:" OFFSTR " sc0 sc1" \
    : "=v"(dst) : "v"(p) : "memory")
// coherent 4B load
#define CLOADW(dst, p) asm volatile( \
    "global_load_dword %0, %1, off sc0 sc1" \
    : "=v"(dst) : "v"(p) : "memory")

__device__ __forceinline__ void st_coh_u16(void* p, unsigned v){
  asm volatile("global_store_short %0, %1, off sc0 sc1" :: "v"(p), "v"(v) : "memory");
}
__device__ __forceinline__ void st_coh_u32(void* p, unsigned v){
  asm volatile("global_store_dword %0, %1, off sc0 sc1" :: "v"(p), "v"(v) : "memory");
}

__device__ __forceinline__ float sigm(float x){ return 1.0f/(1.0f + __expf(-x)); }
__device__ __forceinline__ float tanh_fast(float x){ return 1.0f - 2.0f/(1.0f + __expf(2.0f*x)); }

// ---------------- convert x [B][T][C] f32 -> x_tb [(t*B+b)][C] bf16 ----------------
__global__ __launch_bounds__(256) void convert_x_kernel(const float* __restrict__ x,
                                                        short* __restrict__ xb){
  const long total = (long)TT*BATCH*64;   // 8-elem chunks
  const long stride = (long)gridDim.x * blockDim.x;
  for (long i = (long)blockIdx.x * blockDim.x + threadIdx.x; i < total; i += stride){
    const int c8 = (int)(i & 63);
    const long tb = i >> 6;
    const int b = (int)(tb & (BATCH-1));
    const int t = (int)(tb >> 8);
    const float* src = x + ((long)b*TT + t)*CIN + c8*8;
    const float4 v0 = *(const float4*)(src);
    const float4 v1 = *(const float4*)(src + 4);
    short8 o;
    o[0]=f2bf(v0.x); o[1]=f2bf(v0.y); o[2]=f2bf(v0.z); o[3]=f2bf(v0.w);
    o[4]=f2bf(v1.x); o[5]=f2bf(v1.y); o[6]=f2bf(v1.z); o[7]=f2bf(v1.w);
    *(short8*)(xb + i*8) = o;
  }
}

// ---------------- transpose wx/wh: [512][2048] f32 -> [2048][512] bf16 ----------------
__global__ __launch_bounds__(256) void transpose_w_kernel(
    const float* __restrict__ wx, const float* __restrict__ wh,
    short* __restrict__ wxt, short* __restrict__ wht){
  const float* src = blockIdx.z ? wh : wx;
  short* dst = blockIdx.z ? wht : wxt;
  __shared__ float tile[32][33];
  const int nt = blockIdx.x << 5;
  const int kt = blockIdx.y << 5;
  const int tx = threadIdx.x & 31, ty = threadIdx.x >> 5;
  #pragma unroll
  for (int i = 0; i < 32; i += 8)
    tile[ty+i][tx] = src[(long)(kt+ty+i)*ZN + nt+tx];
  __syncthreads();
  #pragma unroll
  for (int i = 0; i < 32; i += 8)
    dst[(long)(nt+ty+i)*512 + kt+tx] = f2bf(tile[tx][ty+i]);
}

// ---------------- xpart GEMM with XCD panel swizzle ----------------
__global__ __launch_bounds__(256) void gemm_xpart_kernel(
    const short* __restrict__ A, const short* __restrict__ Bt,
    const float* __restrict__ bias, short* __restrict__ Co){
  __shared__ short As[128*32];
  __shared__ short Bs[128*32];
  const int wg = blockIdx.x;
  const int xcd = wg & 7;
  const int ii = wg >> 3;                       // 0..2047 per xcd
  const long m0 = (long)(xcd*128 + (ii >> 4)) << 7;
  const long n0 = (long)(ii & 15) << 7;
  const int tid = threadIdx.x;
  const int lane = tid & 63;
  const int wave = tid >> 6;
  const int wm = wave & 1, wn = wave >> 1;
  f32x4 acc[4][4] = {};
  const int srow = tid >> 2;
  const int sseg = tid & 3;
  const long aoff = (m0 + srow) * 512 + sseg * 8;
  const long boff = (n0 + srow) * 512 + sseg * 8;
  short* ldsa = &As[tid * 8];
  short* ldsb = &Bs[tid * 8];
  for (int k0 = 0; k0 < 512; k0 += 32){
    __syncthreads();
    GLD16(A + aoff + k0, ldsa);
    GLD16(A + aoff + 64*512 + k0, ldsa + 2048);
    GLD16(Bt + boff + k0, ldsb);
    GLD16(Bt + boff + 64*512 + k0, ldsb + 2048);
    __syncthreads();
    const int kb = (lane >> 4) * 8;
    short8 af[4], bf[4];
    #pragma unroll
    for (int mi = 0; mi < 4; mi++) af[mi] = *(const short8*)&As[(wm*64 + mi*16 + (lane&15))*32 + kb];
    #pragma unroll
    for (int ni = 0; ni < 4; ni++) bf[ni] = *(const short8*)&Bs[(wn*64 + ni*16 + (lane&15))*32 + kb];
    #pragma unroll
    for (int mi = 0; mi < 4; mi++)
      #pragma unroll
      for (int ni = 0; ni < 4; ni++)
        acc[mi][ni] = __builtin_amdgcn_mfma_f32_16x16x32_bf16(af[mi], bf[ni], acc[mi][ni], 0, 0, 0);
  }
  #pragma unroll
  for (int ni = 0; ni < 4; ni++){
    const long col = n0 + wn*64 + ni*16 + (lane & 15);
    const float bv = bias[col];
    #pragma unroll
    for (int mi = 0; mi < 4; mi++){
      const long row = m0 + wm*64 + mi*16 + ((lane >> 4) << 2);
      #pragma unroll
      for (int r = 0; r < 4; r++)
        Co[(row + r)*ZN + col] = f2bf(acc[mi][ni][r] + bv);
    }
  }
}

// ---------------- persistent LSTM recurrence ----------------
// 512 WGs x 256 thr, 2 WG/CU: bg = blockIdx>>5 (16 rows), cg = blockIdx&31
// (16 ucols). blockIdx i and i+256 share a CU and have different bgs ->
// independent barrier groups overlap their latency phases on the CU.
// 4 waves/WG, wave = 1 gate x 16 ucols x FULL K=512 register-held wh
// (64 VGPR). h(t) staged once/WG into [k8][row] LDS (conflict-free, R6-
// validated); A-read contiguous. Gate exchange via stride-19 zpart (R5-
// validated). Barrier: h store(sc) -> vmcnt(0) -> sync -> tid0 flag store;
// wave0 polls 32 flags with s_sleep backoff; out-store + prefetch overlap.
__global__ __launch_bounds__(256, 2) void lstm_persist_kernel(
    const short* __restrict__ xpart, const float* __restrict__ dones,
    const short* __restrict__ wht, short* __restrict__ hb0,
    short* __restrict__ hb1, unsigned* __restrict__ flags,
    float* __restrict__ out){
  __shared__ short h_lds[8192];          // [k8=64][row=16][8] = 16KB
  __shared__ float zpart[64*19 + 16];    // ~4.9KB
  const int tid = threadIdx.x;
  const int l = tid & 63;
  const int wv = tid >> 6;           // 0..3 = gate
  const int bg = blockIdx.x >> 5;    // 0..15
  const int cg = blockIdx.x & 31;    // 0..31
  const int rb = bg << 4;
  const int uc = cg << 4;
  const int j = l & 15;
  const int hq = l >> 4;

  // ---- loop-invariant B fragments: gate wv, col uc+j, K=512 (16 chunks) ----
  short8 bfr[16];
  {
    const short* wsrc = wht + ((long)(wv*512 + uc + j))*512 + hq*8;
    #pragma unroll
    for (int m = 0; m < 16; m++)
      bfr[m] = *(const short8*)(wsrc + m*32);
  }

  // ---- staging mapping: thread -> (row, 4 k8-chunks of 32 cols) ----
  const int srow = tid & 15;
  const int skg  = tid >> 4;                        // 0..15
  const long sgoff = (long)(rb + srow)*UU + skg*32; // u16 index
  short* sdst = h_lds + skg*512 + srow*8;           // u16 index

  // ---- epilogue mapping: one (row,ucol) per thread ----
  const int erow = tid >> 4;        // 0..15
  const int euj  = tid & 15;        // 0..15
  const int eucol = uc + euj;
  const int row  = rb + erow;

  unsigned* fl = flags + bg*32;
  const unsigned short* xp16 = (const unsigned short*)xpart;

  float c = 0.0f;
  float dn;
  unsigned short xp[4];
  dn = dones[(long)row*TT];
  #pragma unroll
  for (int g = 0; g < 4; g++)
    xp[g] = xp16[(long)row*ZN + (g<<9) + eucol];

  for (int t = 0; t < TT; t++){
    // ---- stage h(t) -> LDS [k8][row] (coherent; released by prev barrier) ----
    {
      const short* hs = ((t & 1) ? hb1 : hb0) + sgoff;
      short8 v0, v1, v2, v3;
      CLOAD(v0, hs, "0"); CLOAD(v1, hs, "16"); CLOAD(v2, hs, "32"); CLOAD(v3, hs, "48");
      asm volatile("s_waitcnt vmcnt(0)" ::: "memory");
      *(short8*)(sdst      ) = v0;
      *(short8*)(sdst + 128) = v1;
      *(short8*)(sdst + 256) = v2;
      *(short8*)(sdst + 384) = v3;
    }
    __syncthreads();
    // ---- A-frags (contiguous LDS) + 2-chain MFMA, full K=512 ----
    const short* abase = h_lds + l*8;   // u16 idx; chunk m at +m*512
    f32x4 acc0 = {}, acc1 = {};
    #pragma unroll
    for (int m = 0; m < 16; m += 2){
      const short8 a0 = *(const short8*)(abase + m*512);
      const short8 a1 = *(const short8*)(abase + m*512 + 512);
      acc0 = __builtin_amdgcn_mfma_f32_16x16x32_bf16(a0, bfr[m],   acc0, 0, 0, 0);
      acc1 = __builtin_amdgcn_mfma_f32_16x16x32_bf16(a1, bfr[m+1], acc1, 0, 0, 0);
    }
    const f32x4 acc = acc0 + acc1;
    // ---- publish z (stride-19, ~2-way max) ----
    const int zl = wv*16 + j;
    #pragma unroll
    for (int r = 0; r < 4; r++)
      zpart[zl*19 + hq*4 + r] = acc[r];
    __syncthreads();
    // ---- gates (one (row,ucol) per thread) ----
    const float keep = 1.0f - dn;
    const float cold = c * keep;
    const float z0 = bf2f(xp[0]) + keep*zpart[(0*16 + euj)*19 + erow];
    const float z1 = bf2f(xp[1]) + keep*zpart[(1*16 + euj)*19 + erow];
    const float z2 = bf2f(xp[2]) + keep*zpart[(2*16 + euj)*19 + erow];
    const float z3 = bf2f(xp[3]) + keep*zpart[(3*16 + euj)*19 + erow];
    const float gi = sigm(z0);
    const float gf = sigm(z1);
    const float go = sigm(z2);
    const float gu = tanh_fast(z3);
    const float cn = gf*cold + gi*gu;
    const float hn = go * tanh_fast(cn);
    c = cn;
    if (t == TT-1){
      out[(long)row*TT*UU + (long)t*UU + eucol] = hn;
      float* s = out + (long)BATCH*TT*UU;
      s[(long)row*2*UU + eucol] = cn;
      s[(long)row*2*UU + UU + eucol] = hn;
    } else {
      // release: h(t+1) store -> drain -> WG sync -> flag
      short* hdst = (t & 1) ? hb0 : hb1;
      st_coh_u16(hdst + (long)row*UU + eucol, (unsigned)(unsigned short)f2bf(hn));
      asm volatile("s_waitcnt vmcnt(0)" ::: "memory");
      __syncthreads();                      // also protects h_lds/zpart reuse
      if (tid == 0) st_coh_u32(fl + cg, (unsigned)(t+1));
      // overlap with poll: out-store + next-step prefetch (cached paths)
      out[(long)row*TT*UU + (long)t*UU + eucol] = hn;
      dn = dones[(long)row*TT + (t+1)];
      const long xb = ((long)(t+1)*BATCH + row)*ZN + eucol;
      #pragma unroll
      for (int g = 0; g < 4; g++)
        xp[g] = xp16[xb + (g<<9)];
      // single-wave poll of the bg's 32 flags, with backoff
      if (wv == 0){
        const unsigned tgt = (unsigned)(t+1);
        unsigned v;
        for (;;){
          CLOADW(v, fl + (l & 31));
          asm volatile("s_waitcnt vmcnt(0)" ::: "memory");
          if (__all((int)(v >= tgt))) break;
          __builtin_amdgcn_s_sleep(1);
        }
      }
      __syncthreads();                      // release all waves
    }
  }
}

extern "C" void kernel_launch(void* const* d_in, const int* in_sizes, int n_in,
                              void* d_out, int out_size, void* d_ws, size_t ws_size,
                              hipStream_t stream){
  const float* x     = (const float*)d_in[0];
  const float* dones = (const float*)d_in[1];
  const float* wx    = (const float*)d_in[2];
  const float* wh    = (const float*)d_in[3];
  const float* b     = (const float*)d_in[4];
  float* out = (float*)d_out;
  char* ws = (char*)d_ws;
  short* x_tb  = (short*)(ws);                    // 134,217,728 B
  short* wx_t  = (short*)(ws + 134217728L);       //   2,097,152 B
  short* wh_t  = (short*)(ws + 136314880L);       //   2,097,152 B
  short* xpart = (short*)(ws + 138412032L);       // 536,870,912 B
  short* hb0   = (short*)(ws + 675282944L);       //     262,144 B
  short* hb1   = (short*)(ws + 675545088L);       //     262,144 B
  unsigned* flags = (unsigned*)(ws + 675807232L); //       2,048 B

  hipMemsetAsync(hb0, 0, 262144, stream);
  hipMemsetAsync(flags, 0, 2048, stream);
  convert_x_kernel<<<2048, 256, 0, stream>>>(x, x_tb);
  transpose_w_kernel<<<dim3(64,16,2), 256, 0, stream>>>(wx, wh, wx_t, wh_t);
  gemm_xpart_kernel<<<16384, 256, 0, stream>>>(x_tb, wx_t, b, xpart);
  lstm_persist_kernel<<<512, 256, 0, stream>>>(xpart, dones, wh_t, hb0, hb1, flags, out);
}

// Round 9
// 2008.766 us; speedup vs baseline: 1.3515x; 1.3515x over previous
//
#include <hip/hip_runtime.h>

#define BATCH 256
#define TT 512
#define CIN 512
#define UU 512
#define ZN 2048
#define BT (BATCH*TT)

typedef __attribute__((ext_vector_type(8))) short short8;
typedef __attribute__((ext_vector_type(4))) float f32x4;

__device__ __forceinline__ short f2bf(float f){
  unsigned u = __float_as_uint(f);
  u += 0x7fffu + ((u >> 16) & 1u);   // round-to-nearest-even
  return (short)(u >> 16);
}
__device__ __forceinline__ float bf2f(unsigned short s){
  unsigned u = ((unsigned)s) << 16;
  return __uint_as_float(u);
}

#define GLD16(g, l) __builtin_amdgcn_global_load_lds( \
    (const __attribute__((address_space(1))) void*)(g), \
    (__attribute__((address_space(3))) void*)(l), 16, 0, 0)

// coherent (device-scope, MALL) 16B load with immediate offset
#define CLOAD(dst, p, OFFSTR) asm volatile( \
    "global_load_dwordx4 %0, %1, off offset:" OFFSTR " sc0 sc1" \
    : "=v"(dst) : "v"(p) : "memory")
// coherent 4B load
#define CLOADW(dst, p) asm volatile( \
    "global_load_dword %0, %1, off sc0 sc1" \
    : "=v"(dst) : "v"(p) : "memory")

__device__ __forceinline__ void st_coh_u16(void* p, unsigned v){
  asm volatile("global_store_short %0, %1, off sc0 sc1" :: "v"(p), "v"(v) : "memory");
}
__device__ __forceinline__ void st_coh_u32(void* p, unsigned v){
  asm volatile("global_store_dword %0, %1, off sc0 sc1" :: "v"(p), "v"(v) : "memory");
}

__device__ __forceinline__ float sigm(float x){ return 1.0f/(1.0f + __expf(-x)); }
__device__ __forceinline__ float tanh_fast(float x){ return 1.0f - 2.0f/(1.0f + __expf(2.0f*x)); }

// ---------------- transpose wx/wh: [512][2048] f32 -> [2048][512] bf16 ----------------
__global__ __launch_bounds__(256) void transpose_w_kernel(
    const float* __restrict__ wx, const float* __restrict__ wh,
    short* __restrict__ wxt, short* __restrict__ wht){
  const float* src = blockIdx.z ? wh : wx;
  short* dst = blockIdx.z ? wht : wxt;
  __shared__ float tile[32][33];
  const int nt = blockIdx.x << 5;
  const int kt = blockIdx.y << 5;
  const int tx = threadIdx.x & 31, ty = threadIdx.x >> 5;
  #pragma unroll
  for (int i = 0; i < 32; i += 8)
    tile[ty+i][tx] = src[(long)(kt+ty+i)*ZN + nt+tx];
  __syncthreads();
  #pragma unroll
  for (int i = 0; i < 32; i += 8)
    dst[(long)(nt+ty+i)*512 + kt+tx] = f2bf(tile[tx][ty+i]);
}

// ---------------- xpart GEMM (convert fused into A-staging) ----------------
// A = x [B][T][C] f32 read directly; A-row m of the t-major virtual matrix
// maps to (t = m>>8, b = m&255) -> x + (b*TT + t)*CIN. Reg-stage A (f32 ->
// bf16 -> ds_write 16B/thread, same LDS slot layout as global_load_lds);
// B (weights, bf16) via global_load_lds. XCD panel swizzle as before.
__global__ __launch_bounds__(256) void gemm_xpart_kernel(
    const float* __restrict__ x, const short* __restrict__ Bt,
    const float* __restrict__ bias, short* __restrict__ Co){
  __shared__ short As[128*32];
  __shared__ short Bs[128*32];
  const int wg = blockIdx.x;
  const int xcd = wg & 7;
  const int ii = wg >> 3;                       // 0..2047 per xcd
  const long m0 = (long)(xcd*128 + (ii >> 4)) << 7;   // multiple of 128
  const long n0 = (long)(ii & 15) << 7;
  const int tid = threadIdx.x;
  const int lane = tid & 63;
  const int wave = tid >> 6;
  const int wm = wave & 1, wn = wave >> 1;
  f32x4 acc[4][4] = {};
  const int srow = tid >> 2;   // 0..63
  const int sseg = tid & 3;
  const long mA = m0 + srow;
  const long mB2 = m0 + srow + 64;
  const float* aptrA = x + ((long)(mA  & 255)*TT + (mA  >> 8))*CIN + sseg*8;
  const float* aptrB = x + ((long)(mB2 & 255)*TT + (mB2 >> 8))*CIN + sseg*8;
  const long boff = (n0 + srow) * 512 + sseg * 8;
  short* ldsa = &As[tid * 8];
  short* ldsb = &Bs[tid * 8];
  for (int k0 = 0; k0 < 512; k0 += 32){
    __syncthreads();
    GLD16(Bt + boff + k0, ldsb);
    GLD16(Bt + boff + 64*512 + k0, ldsb + 2048);
    const float4 a0 = *(const float4*)(aptrA + k0);
    const float4 a1 = *(const float4*)(aptrA + k0 + 4);
    const float4 b0 = *(const float4*)(aptrB + k0);
    const float4 b1 = *(const float4*)(aptrB + k0 + 4);
    short8 sa, sb;
    sa[0]=f2bf(a0.x); sa[1]=f2bf(a0.y); sa[2]=f2bf(a0.z); sa[3]=f2bf(a0.w);
    sa[4]=f2bf(a1.x); sa[5]=f2bf(a1.y); sa[6]=f2bf(a1.z); sa[7]=f2bf(a1.w);
    sb[0]=f2bf(b0.x); sb[1]=f2bf(b0.y); sb[2]=f2bf(b0.z); sb[3]=f2bf(b0.w);
    sb[4]=f2bf(b1.x); sb[5]=f2bf(b1.y); sb[6]=f2bf(b1.z); sb[7]=f2bf(b1.w);
    *(short8*)ldsa = sa;
    *(short8*)(ldsa + 2048) = sb;
    __syncthreads();
    const int kb = (lane >> 4) * 8;
    short8 af[4], bf[4];
    #pragma unroll
    for (int mi = 0; mi < 4; mi++) af[mi] = *(const short8*)&As[(wm*64 + mi*16 + (lane&15))*32 + kb];
    #pragma unroll
    for (int ni = 0; ni < 4; ni++) bf[ni] = *(const short8*)&Bs[(wn*64 + ni*16 + (lane&15))*32 + kb];
    #pragma unroll
    for (int mi = 0; mi < 4; mi++)
      #pragma unroll
      for (int ni = 0; ni < 4; ni++)
        acc[mi][ni] = __builtin_amdgcn_mfma_f32_16x16x32_bf16(af[mi], bf[ni], acc[mi][ni], 0, 0, 0);
  }
  #pragma unroll
  for (int ni = 0; ni < 4; ni++){
    const long col = n0 + wn*64 + ni*16 + (lane & 15);
    const float bv = bias[col];
    #pragma unroll
    for (int mi = 0; mi < 4; mi++){
      const long row = m0 + wm*64 + mi*16 + ((lane >> 4) << 2);
      #pragma unroll
      for (int r = 0; r < 4; r++)
        Co[(row + r)*ZN + col] = f2bf(acc[mi][ni][r] + bv);
    }
  }
}

// ---------------- persistent LSTM recurrence (validated R5 structure) ----------------
// 256 WGs x 512 thr: bg = blockIdx&15 (16 rows), cg = blockIdx>>4 (32 ucols).
// 8 waves/WG; wave wv = gate (wv>>1) x 16 ucols, FULL K=512 register-held wh
// (64 VGPR). h(t) staged once/WG into [k8][row] LDS (conflict-free);
// A-read contiguous. Gate exchange via stride-19 zpart. Barrier: h store(sc)
// -> vmcnt(0) -> sync -> tid0 flag store; wave0 polls 16 flags with s_sleep
// backoff; out-store + xpart/dones prefetch overlap the poll.
__global__ __launch_bounds__(512, 2) void lstm_persist_kernel(
    const short* __restrict__ xpart, const float* __restrict__ dones,
    const short* __restrict__ wht, short* __restrict__ hb0,
    short* __restrict__ hb1, unsigned* __restrict__ flags,
    float* __restrict__ out){
  __shared__ short h_lds[8192];          // [k8=64][row=16][8] = 16KB
  __shared__ float zpart[128*19 + 16];
  const int tid = threadIdx.x;
  const int lane = tid & 63;
  const int wv = tid >> 6;          // 0..7
  const int bg = blockIdx.x & 15;
  const int cg = blockIdx.x >> 4;   // 0..15
  const int rb = bg << 4;           // batch row base
  const int uc = cg << 5;           // u-col base (32 per WG)
  const int j = lane & 15;
  const int hq = lane >> 4;
  const int g_w = wv >> 1;                    // gate this wave computes
  const int ucl = ((wv & 1) << 4) + j;        // local ucol of this lane's B-col
  const int zl = g_w*32 + ucl;                // local z-col 0..127

  // ---- loop-invariant B fragments ----
  short8 bfr[16];
  {
    const short* wsrc = wht + ((long)(g_w*512 + uc + ucl))*512 + hq*8;
    #pragma unroll
    for (int m = 0; m < 16; m++)
      bfr[m] = *(const short8*)(wsrc + m*32);
  }

  // ---- staging mapping: thread -> (row, 2 k8-chunks of 16 cols) ----
  const int srow = tid & 15;
  const int skg  = tid >> 4;                        // 0..31
  const long sgoff = (long)(rb + srow)*UU + skg*16; // u16 index
  short* sdst = h_lds + skg*256 + srow*8;           // u16 index

  // ---- epilogue mapping: one (row,ucol) per thread ----
  const int erow = tid >> 5;        // 0..15
  const int euj  = tid & 31;        // 0..31
  const int eucol = uc + euj;
  const int row  = rb + erow;

  unsigned* fl = flags + bg*16;
  const unsigned short* xp16 = (const unsigned short*)xpart;

  float c = 0.0f;
  float dn;
  unsigned short xp[4];
  dn = dones[(long)row*TT];
  #pragma unroll
  for (int g = 0; g < 4; g++)
    xp[g] = xp16[(long)row*ZN + (g<<9) + eucol];

  for (int t = 0; t < TT; t++){
    // ---- stage h(t) -> LDS [k8][row] (coherent; released by prev barrier) ----
    {
      const short* hs = ((t & 1) ? hb1 : hb0) + sgoff;
      short8 v0, v1;
      CLOAD(v0, hs, "0"); CLOAD(v1, hs, "16");
      asm volatile("s_waitcnt vmcnt(0)" ::: "memory");
      *(short8*)(sdst      ) = v0;
      *(short8*)(sdst + 128) = v1;
    }
    __syncthreads();
    // ---- A-frags (contiguous LDS) + 2-chain MFMA, full K=512 ----
    const short* abase = h_lds + lane*8;   // u16 idx; chunk m at +m*512
    f32x4 acc0 = {}, acc1 = {};
    #pragma unroll
    for (int m = 0; m < 16; m += 2){
      const short8 a0 = *(const short8*)(abase + m*512);
      const short8 a1 = *(const short8*)(abase + m*512 + 512);
      acc0 = __builtin_amdgcn_mfma_f32_16x16x32_bf16(a0, bfr[m],   acc0, 0, 0, 0);
      acc1 = __builtin_amdgcn_mfma_f32_16x16x32_bf16(a1, bfr[m+1], acc1, 0, 0, 0);
    }
    const f32x4 acc = acc0 + acc1;
    // ---- publish z (stride-19, ~2-way max) ----
    #pragma unroll
    for (int r = 0; r < 4; r++)
      zpart[zl*19 + hq*4 + r] = acc[r];
    __syncthreads();
    // ---- gates (one (row,ucol) per thread) ----
    const float keep = 1.0f - dn;
    const float cold = c * keep;
    const float z0 = bf2f(xp[0]) + keep*zpart[(0*32 + euj)*19 + erow];
    const float z1 = bf2f(xp[1]) + keep*zpart[(1*32 + euj)*19 + erow];
    const float z2 = bf2f(xp[2]) + keep*zpart[(2*32 + euj)*19 + erow];
    const float z3 = bf2f(xp[3]) + keep*zpart[(3*32 + euj)*19 + erow];
    const float gi = sigm(z0);
    const float gf = sigm(z1);
    const float go = sigm(z2);
    const float gu = tanh_fast(z3);
    const float cn = gf*cold + gi*gu;
    const float hn = go * tanh_fast(cn);
    c = cn;
    if (t == TT-1){
      out[(long)row*TT*UU + (long)t*UU + eucol] = hn;
      float* s = out + (long)BATCH*TT*UU;
      s[(long)row*2*UU + eucol] = cn;
      s[(long)row*2*UU + UU + eucol] = hn;
    } else {
      // release: h(t+1) store -> drain -> WG sync -> flag
      short* hdst = (t & 1) ? hb0 : hb1;
      st_coh_u16(hdst + (long)row*UU + eucol, (unsigned)(unsigned short)f2bf(hn));
      asm volatile("s_waitcnt vmcnt(0)" ::: "memory");
      __syncthreads();                      // also protects h_lds/zpart reuse
      if (tid == 0) st_coh_u32(fl + cg, (unsigned)(t+1));
      // overlap with poll: out-store + next-step prefetch (cached paths)
      out[(long)row*TT*UU + (long)t*UU + eucol] = hn;
      dn = dones[(long)row*TT + (t+1)];
      const long xb = ((long)(t+1)*BATCH + row)*ZN + eucol;
      #pragma unroll
      for (int g = 0; g < 4; g++)
        xp[g] = xp16[xb + (g<<9)];
      // single-wave poll of the bg's 16 flags, with backoff
      if (wv == 0){
        const unsigned tgt = (unsigned)(t+1);
        unsigned v;
        for (;;){
          CLOADW(v, fl + (lane & 15));
          asm volatile("s_waitcnt vmcnt(0)" ::: "memory");
          if (__all((int)(v >= tgt))) break;
          __builtin_amdgcn_s_sleep(1);
        }
      }
      __syncthreads();                      // release all waves
    }
  }
}

extern "C" void kernel_launch(void* const* d_in, const int* in_sizes, int n_in,
                              void* d_out, int out_size, void* d_ws, size_t ws_size,
                              hipStream_t stream){
  const float* x     = (const float*)d_in[0];
  const float* dones = (const float*)d_in[1];
  const float* wx    = (const float*)d_in[2];
  const float* wh    = (const float*)d_in[3];
  const float* b     = (const float*)d_in[4];
  float* out = (float*)d_out;
  char* ws = (char*)d_ws;
  short* xpart = (short*)(ws);                    // 536,870,912 B
  short* wx_t  = (short*)(ws + 536870912L);       //   2,097,152 B
  short* wh_t  = (short*)(ws + 538968064L);       //   2,097,152 B
  short* hb0   = (short*)(ws + 541065216L);       //     262,144 B
  short* hb1   = (short*)(ws + 541327360L);       //     262,144 B
  unsigned* flags = (unsigned*)(ws + 541589504L); //       1,024 B

  hipMemsetAsync(hb0, 0, 262144, stream);
  hipMemsetAsync(flags, 0, 1024, stream);
  transpose_w_kernel<<<dim3(64,16,2), 256, 0, stream>>>(wx, wh, wx_t, wh_t);
  gemm_xpart_kernel<<<16384, 256, 0, stream>>>(x, wx_t, b, xpart);
  lstm_persist_kernel<<<256, 512, 0, stream>>>(xpart, dones, wh_t, hb0, hb1, flags, out);
}

// Round 10
// 1754.601 us; speedup vs baseline: 1.5472x; 1.1449x over previous
//
#include <hip/hip_runtime.h>

#define BATCH 256
#define TT 512
#define CIN 512
#define UU 512
#define ZN 2048
#define BT (BATCH*TT)

typedef __attribute__((ext_vector_type(8))) short short8;
typedef __attribute__((ext_vector_type(4))) float f32x4;
typedef __attribute__((ext_vector_type(4))) unsigned u32x4;

__device__ __forceinline__ short f2bf(float f){
  unsigned u = __float_as_uint(f);
  u += 0x7fffu + ((u >> 16) & 1u);   // round-to-nearest-even
  return (short)(u >> 16);
}
__device__ __forceinline__ float bf2f(unsigned short s){
  unsigned u = ((unsigned)s) << 16;
  return __uint_as_float(u);
}

#define GLD16(g, l) __builtin_amdgcn_global_load_lds( \
    (const __attribute__((address_space(1))) void*)(g), \
    (__attribute__((address_space(3))) void*)(l), 16, 0, 0)

// coherent (device-scope, MALL) 16B load with immediate offset
#define CLOAD(dst, p, OFFSTR) asm volatile( \
    "global_load_dwordx4 %0, %1, off offset:" OFFSTR " sc0 sc1" \
    : "=v"(dst) : "v"(p) : "memory")

__device__ __forceinline__ void st_coh_u32(void* p, unsigned v){
  asm volatile("global_store_dword %0, %1, off sc0 sc1" :: "v"(p), "v"(v) : "memory");
}

__device__ __forceinline__ float sigm(float x){ return 1.0f/(1.0f + __expf(-x)); }
__device__ __forceinline__ float tanh_fast(float x){ return 1.0f - 2.0f/(1.0f + __expf(2.0f*x)); }

// ---------------- convert x [B][T][C] f32 -> x_tb [(t*B+b)][C] bf16 ----------------
__global__ __launch_bounds__(256) void convert_x_kernel(const float* __restrict__ x,
                                                        short* __restrict__ xb){
  const long total = (long)TT*BATCH*64;   // 8-elem chunks
  const long stride = (long)gridDim.x * blockDim.x;
  for (long i = (long)blockIdx.x * blockDim.x + threadIdx.x; i < total; i += stride){
    const int c8 = (int)(i & 63);
    const long tb = i >> 6;
    const int b = (int)(tb & (BATCH-1));
    const int t = (int)(tb >> 8);
    const float* src = x + ((long)b*TT + t)*CIN + c8*8;
    const float4 v0 = *(const float4*)(src);
    const float4 v1 = *(const float4*)(src + 4);
    short8 o;
    o[0]=f2bf(v0.x); o[1]=f2bf(v0.y); o[2]=f2bf(v0.z); o[3]=f2bf(v0.w);
    o[4]=f2bf(v1.x); o[5]=f2bf(v1.y); o[6]=f2bf(v1.z); o[7]=f2bf(v1.w);
    *(short8*)(xb + i*8) = o;
  }
}

// ---------------- transpose wx/wh: [512][2048] f32 -> [2048][512] bf16 ----------------
__global__ __launch_bounds__(256) void transpose_w_kernel(
    const float* __restrict__ wx, const float* __restrict__ wh,
    short* __restrict__ wxt, short* __restrict__ wht){
  const float* src = blockIdx.z ? wh : wx;
  short* dst = blockIdx.z ? wht : wxt;
  __shared__ float tile[32][33];
  const int nt = blockIdx.x << 5;
  const int kt = blockIdx.y << 5;
  const int tx = threadIdx.x & 31, ty = threadIdx.x >> 5;
  #pragma unroll
  for (int i = 0; i < 32; i += 8)
    tile[ty+i][tx] = src[(long)(kt+ty+i)*ZN + nt+tx];
  __syncthreads();
  #pragma unroll
  for (int i = 0; i < 32; i += 8)
    dst[(long)(nt+ty+i)*512 + kt+tx] = f2bf(tile[tx][ty+i]);
}

// ---------------- xpart GEMM (R5-validated GLD16 path, XCD panel swizzle) ----------------
__global__ __launch_bounds__(256) void gemm_xpart_kernel(
    const short* __restrict__ A, const short* __restrict__ Bt,
    const float* __restrict__ bias, short* __restrict__ Co){
  __shared__ short As[128*32];
  __shared__ short Bs[128*32];
  const int wg = blockIdx.x;
  const int xcd = wg & 7;
  const int ii = wg >> 3;                       // 0..2047 per xcd
  const long m0 = (long)(xcd*128 + (ii >> 4)) << 7;
  const long n0 = (long)(ii & 15) << 7;
  const int tid = threadIdx.x;
  const int lane = tid & 63;
  const int wave = tid >> 6;
  const int wm = wave & 1, wn = wave >> 1;
  f32x4 acc[4][4] = {};
  const int srow = tid >> 2;
  const int sseg = tid & 3;
  const long aoff = (m0 + srow) * 512 + sseg * 8;
  const long boff = (n0 + srow) * 512 + sseg * 8;
  short* ldsa = &As[tid * 8];
  short* ldsb = &Bs[tid * 8];
  for (int k0 = 0; k0 < 512; k0 += 32){
    __syncthreads();
    GLD16(A + aoff + k0, ldsa);
    GLD16(A + aoff + 64*512 + k0, ldsa + 2048);
    GLD16(Bt + boff + k0, ldsb);
    GLD16(Bt + boff + 64*512 + k0, ldsb + 2048);
    __syncthreads();
    const int kb = (lane >> 4) * 8;
    short8 af[4], bf[4];
    #pragma unroll
    for (int mi = 0; mi < 4; mi++) af[mi] = *(const short8*)&As[(wm*64 + mi*16 + (lane&15))*32 + kb];
    #pragma unroll
    for (int ni = 0; ni < 4; ni++) bf[ni] = *(const short8*)&Bs[(wn*64 + ni*16 + (lane&15))*32 + kb];
    #pragma unroll
    for (int mi = 0; mi < 4; mi++)
      #pragma unroll
      for (int ni = 0; ni < 4; ni++)
        acc[mi][ni] = __builtin_amdgcn_mfma_f32_16x16x32_bf16(af[mi], bf[ni], acc[mi][ni], 0, 0, 0);
  }
  #pragma unroll
  for (int ni = 0; ni < 4; ni++){
    const long col = n0 + wn*64 + ni*16 + (lane & 15);
    const float bv = bias[col];
    #pragma unroll
    for (int mi = 0; mi < 4; mi++){
      const long row = m0 + wm*64 + mi*16 + ((lane >> 4) << 2);
      #pragma unroll
      for (int r = 0; r < 4; r++)
        Co[(row + r)*ZN + col] = f2bf(acc[mi][ni][r] + bv);
    }
  }
}

// ---------------- persistent LSTM recurrence — tagged-h protocol ----------------
// 256 WGs x 512 thr (1/CU): bg = blockIdx&15 (16 rows), cg = blockIdx>>4
// (32 ucols). Compute structure = R5/R9 validated (wave = gate x 16 ucols,
// full-K register wh; [k8][row] LDS; stride-19 zpart; keep in epilogue).
// Sync: h stored as u32 (bf16<<16 | step-tag) with sc0 sc1 — the store IS
// the release. Staging threads poll their own 16 tagged words until
// tag==t (self-synchronizing; no flags, no drains, 2 syncthreads/step).
// Replay-safe: both ht buffers memset each launch.
__global__ __launch_bounds__(512, 1) void lstm_persist_kernel(
    const short* __restrict__ xpart, const float* __restrict__ dones,
    const short* __restrict__ wht, unsigned* __restrict__ ht0,
    unsigned* __restrict__ ht1, float* __restrict__ out){
  __shared__ short h_lds[8192];          // [k8=64][row=16][8] = 16KB
  __shared__ float zpart[128*19 + 16];
  const int tid = threadIdx.x;
  const int lane = tid & 63;
  const int wv = tid >> 6;          // 0..7
  const int bg = blockIdx.x & 15;
  const int cg = blockIdx.x >> 4;   // 0..15
  const int rb = bg << 4;           // batch row base
  const int uc = cg << 5;           // u-col base (32 per WG)
  const int j = lane & 15;
  const int hq = lane >> 4;
  const int g_w = wv >> 1;                    // gate this wave computes
  const int ucl = ((wv & 1) << 4) + j;        // local ucol of this lane's B-col
  const int zl = g_w*32 + ucl;                // local z-col 0..127

  // ---- loop-invariant B fragments ----
  short8 bfr[16];
  {
    const short* wsrc = wht + ((long)(g_w*512 + uc + ucl))*512 + hq*8;
    #pragma unroll
    for (int m = 0; m < 16; m++)
      bfr[m] = *(const short8*)(wsrc + m*32);
  }

  // ---- staging mapping: thread -> (row srow, u32 cols skg*16..+15) ----
  const int srow = tid & 15;
  const int skg  = tid >> 4;                        // 0..31
  const long hoff = (long)(rb + srow)*UU + skg*16;  // u32 index
  short* sdst = h_lds + skg*256 + srow*8;           // u16 index

  // ---- epilogue mapping: one (row,ucol) per thread ----
  const int erow = tid >> 5;        // 0..15
  const int euj  = tid & 31;        // 0..31
  const int eucol = uc + euj;
  const int row  = rb + erow;

  const unsigned short* xp16 = (const unsigned short*)xpart;

  float c = 0.0f;
  float dn;
  unsigned short xp[4];
  dn = dones[(long)row*TT];
  #pragma unroll
  for (int g = 0; g < 4; g++)
    xp[g] = xp16[(long)row*ZN + (g<<9) + eucol];

  for (int t = 0; t < TT; t++){
    // ---- stage h(t): poll own 16 tagged words until tag==t, pack -> LDS ----
    {
      const unsigned* hs = ((t & 1) ? ht1 : ht0) + hoff;
      const unsigned tg = (unsigned)t;
      u32x4 w0, w1, w2, w3;
      for (;;){
        CLOAD(w0, hs, "0"); CLOAD(w1, hs, "16");
        CLOAD(w2, hs, "32"); CLOAD(w3, hs, "48");
        asm volatile("s_waitcnt vmcnt(0)" ::: "memory");
        const unsigned d = (w0[0]^tg)|(w0[1]^tg)|(w0[2]^tg)|(w0[3]^tg)
                         | (w1[0]^tg)|(w1[1]^tg)|(w1[2]^tg)|(w1[3]^tg)
                         | (w2[0]^tg)|(w2[1]^tg)|(w2[2]^tg)|(w2[3]^tg)
                         | (w3[0]^tg)|(w3[1]^tg)|(w3[2]^tg)|(w3[3]^tg);
        if (__all((int)((d & 0xffffu) == 0u))) break;
        __builtin_amdgcn_s_sleep(1);
      }
      u32x4 pa, pb;
      pa[0] = (w0[0]>>16) | (w0[1] & 0xffff0000u);
      pa[1] = (w0[2]>>16) | (w0[3] & 0xffff0000u);
      pa[2] = (w1[0]>>16) | (w1[1] & 0xffff0000u);
      pa[3] = (w1[2]>>16) | (w1[3] & 0xffff0000u);
      pb[0] = (w2[0]>>16) | (w2[1] & 0xffff0000u);
      pb[1] = (w2[2]>>16) | (w2[3] & 0xffff0000u);
      pb[2] = (w3[0]>>16) | (w3[1] & 0xffff0000u);
      pb[3] = (w3[2]>>16) | (w3[3] & 0xffff0000u);
      *(u32x4*)(sdst)       = pa;   // k8 chunk 2*skg
      *(u32x4*)(sdst + 128) = pb;   // k8 chunk 2*skg+1
    }
    __syncthreads();
    // ---- A-frags (contiguous LDS) + 2-chain MFMA, full K=512 ----
    const short* abase = h_lds + lane*8;   // u16 idx; chunk m at +m*512
    f32x4 acc0 = {}, acc1 = {};
    #pragma unroll
    for (int m = 0; m < 16; m += 2){
      const short8 a0 = *(const short8*)(abase + m*512);
      const short8 a1 = *(const short8*)(abase + m*512 + 512);
      acc0 = __builtin_amdgcn_mfma_f32_16x16x32_bf16(a0, bfr[m],   acc0, 0, 0, 0);
      acc1 = __builtin_amdgcn_mfma_f32_16x16x32_bf16(a1, bfr[m+1], acc1, 0, 0, 0);
    }
    const f32x4 acc = acc0 + acc1;
    // ---- publish z (stride-19) ----
    #pragma unroll
    for (int r = 0; r < 4; r++)
      zpart[zl*19 + hq*4 + r] = acc[r];
    __syncthreads();
    // ---- gates (one (row,ucol) per thread) ----
    const float keep = 1.0f - dn;
    const float cold = c * keep;
    const float z0 = bf2f(xp[0]) + keep*zpart[(0*32 + euj)*19 + erow];
    const float z1 = bf2f(xp[1]) + keep*zpart[(1*32 + euj)*19 + erow];
    const float z2 = bf2f(xp[2]) + keep*zpart[(2*32 + euj)*19 + erow];
    const float z3 = bf2f(xp[3]) + keep*zpart[(3*32 + euj)*19 + erow];
    const float gi = sigm(z0);
    const float gf = sigm(z1);
    const float go = sigm(z2);
    const float gu = tanh_fast(z3);
    const float cn = gf*cold + gi*gu;
    const float hn = go * tanh_fast(cn);
    c = cn;
    if (t == TT-1){
      out[(long)row*TT*UU + (long)t*UU + eucol] = hn;
      float* s = out + (long)BATCH*TT*UU;
      s[(long)row*2*UU + eucol] = cn;
      s[(long)row*2*UU + UU + eucol] = hn;
    } else {
      // release = the tagged store itself (fire-and-forget, device-coherent)
      unsigned* hd = (t & 1) ? ht0 : ht1;
      const unsigned hv = ((unsigned)(unsigned short)f2bf(hn) << 16) | (unsigned)(t+1);
      st_coh_u32(hd + (long)row*UU + eucol, hv);
      // off-path: out-store + next-step prefetches (overlap next poll's RTT)
      out[(long)row*TT*UU + (long)t*UU + eucol] = hn;
      dn = dones[(long)row*TT + (t+1)];
      const long xb = ((long)(t+1)*BATCH + row)*ZN + eucol;
      #pragma unroll
      for (int g = 0; g < 4; g++)
        xp[g] = xp16[xb + (g<<9)];
    }
  }
}

extern "C" void kernel_launch(void* const* d_in, const int* in_sizes, int n_in,
                              void* d_out, int out_size, void* d_ws, size_t ws_size,
                              hipStream_t stream){
  const float* x     = (const float*)d_in[0];
  const float* dones = (const float*)d_in[1];
  const float* wx    = (const float*)d_in[2];
  const float* wh    = (const float*)d_in[3];
  const float* b     = (const float*)d_in[4];
  float* out = (float*)d_out;
  char* ws = (char*)d_ws;
  short* x_tb  = (short*)(ws);                    // 134,217,728 B
  short* wx_t  = (short*)(ws + 134217728L);       //   2,097,152 B
  short* wh_t  = (short*)(ws + 136314880L);       //   2,097,152 B
  short* xpart = (short*)(ws + 138412032L);       // 536,870,912 B
  unsigned* ht0 = (unsigned*)(ws + 675282944L);   //     524,288 B
  unsigned* ht1 = (unsigned*)(ws + 675807232L);   //     524,288 B

  hipMemsetAsync(ht0, 0, 524288, stream);
  hipMemsetAsync(ht1, 0, 524288, stream);
  convert_x_kernel<<<2048, 256, 0, stream>>>(x, x_tb);
  transpose_w_kernel<<<dim3(64,16,2), 256, 0, stream>>>(wx, wh, wx_t, wh_t);
  gemm_xpart_kernel<<<16384, 256, 0, stream>>>(x_tb, wx_t, b, xpart);
  lstm_persist_kernel<<<256, 512, 0, stream>>>(xpart, dones, wh_t, ht0, ht1, out);
}